// Round 14
// baseline (172.017 us; speedup 1.0000x reference)
//
#include <hip/hip_runtime.h>
#include <hip/hip_fp16.h>
#include <math.h>

// ---------------------------------------------------------------------------
// Fused transformer block: QKV proj -> masked MHA -> out proj + residual -> LN
// B=2, S=2048, D=1024, H=16, hd=64.  All GEMM/attention compute in fp16 MFMA
// with fp32 accumulation; final output fp32.
// ---------------------------------------------------------------------------

typedef _Float16 half8 __attribute__((ext_vector_type(8)));
typedef _Float16 half4v __attribute__((ext_vector_type(4)));
typedef float f32x4 __attribute__((ext_vector_type(4)));

#define MFMA16(a, b, c) __builtin_amdgcn_mfma_f32_16x16x32_f16((a), (b), (c), 0, 0, 0)

static __device__ __forceinline__ half8 cvt8(float4 a, float4 b) {
    half8 h;
    h[0] = (_Float16)a.x; h[1] = (_Float16)a.y; h[2] = (_Float16)a.z; h[3] = (_Float16)a.w;
    h[4] = (_Float16)b.x; h[5] = (_Float16)b.y; h[6] = (_Float16)b.z; h[7] = (_Float16)b.w;
    return h;
}

// ---------------------------------------------------------------------------
// Unified prep kernel (one launch):
//   blocks [0, 4096):    W[k][n] fp32 -> Wt[n][k] fp16 for wq/wk/wv/wo
//   blocks [4096, 12288): mask -> multiplicative fp16 keep (1=attend, 0=mask)
//                         with per-block dtype self-detection (in-bounds for
//                         both dtypes; misdetect prob (1/8)^256 ~ 0).
// ---------------------------------------------------------------------------
__global__ __launch_bounds__(256) void prep_kernel(
    const float* __restrict__ W0, const float* __restrict__ W1,
    const float* __restrict__ W2, const float* __restrict__ W3,
    _Float16* __restrict__ WtBase,
    const void* __restrict__ mask, _Float16* __restrict__ km) {
    const int bid = blockIdx.x;
    const int tid = threadIdx.x;
    if (bid < 4096) {
        __shared__ float t[32][33];
        const int z = bid >> 10, tile = bid & 1023;
        const float* W = (z == 0) ? W0 : ((z == 1) ? W1 : ((z == 2) ? W2 : W3));
        _Float16* Wt = WtBase + (size_t)z * 1024 * 1024;
        const int tx = tid & 31, ty = tid >> 5;
        const int n0 = (tile & 31) * 32, k0 = (tile >> 5) * 32;
#pragma unroll
        for (int i = 0; i < 4; ++i)
            t[ty + i * 8][tx] = W[(size_t)(k0 + ty + i * 8) * 1024 + n0 + tx];
        __syncthreads();
#pragma unroll
        for (int i = 0; i < 4; ++i)
            Wt[(size_t)(n0 + ty + i * 8) * 1024 + k0 + tx] = (_Float16)t[tx][ty + i * 8];
    } else {
        __shared__ int any;
        const int b = bid - 4096;               // 0..8191, 1024 elements each
        const int i = (b * 256 + tid) * 4;      // element index
        const unsigned v = ((const unsigned*)mask)[b * 256 + tid];
        if (tid == 0) any = 0;
        __syncthreads();
        if (v > 1u) atomicOr(&any, 1);
        __syncthreads();
        const bool bytemode = (any != 0);
        int v0, v1, v2, v3;
        if (bytemode) {
            const unsigned int w = *(const unsigned int*)((const unsigned char*)mask + i);
            v0 = w & 0xff; v1 = (w >> 8) & 0xff; v2 = (w >> 16) & 0xff; v3 = (w >> 24) & 0xff;
        } else {
            const int4 w = *(const int4*)((const int*)mask + i);
            v0 = w.x; v1 = w.y; v2 = w.z; v3 = w.w;
        }
        const _Float16 ONE = (_Float16)1.0f;
        const _Float16 ZER = (_Float16)0.0f;
        half4v o = { v0 ? ZER : ONE, v1 ? ZER : ONE, v2 ? ZER : ONE, v3 ? ZER : ONE };
        *(half4v*)(km + i) = o;
    }
}

// ---------------------------------------------------------------------------
// QKV projection GEMM (r14): double-buffered LDS, 1 barrier/K-step, fused
// fp32->fp16 cast on A. grid.z selects q/k/v.
//   z==0/1: write head layout [b,h,s,d] fp16 (Qh/Kh).
//   z==2:   write V TRANSPOSED directly: Vt[bh][d][s] — each thread's 4 accs
//           (j=0..3) are 4 consecutive s at fixed d -> aligned half4 store.
//           Removes the separate vtrans kernel entirely.
// ---------------------------------------------------------------------------
__global__ __launch_bounds__(256) void gemm_qkv_kernel(
    const float* __restrict__ Aq, const float* __restrict__ Ak, const float* __restrict__ Av,
    const _Float16* __restrict__ Btbase,
    const float* __restrict__ bq, const float* __restrict__ bk, const float* __restrict__ bv,
    _Float16* __restrict__ Hbase, _Float16* __restrict__ Vtp) {
    constexpr int K = 1024;
    const int z = blockIdx.z;
    const float* A = (z == 0) ? Aq : ((z == 1) ? Ak : Av);
    const _Float16* Bt = Btbase + (size_t)z * 1024 * 1024;
    const float* bias = (z == 0) ? bq : ((z == 1) ? bk : bv);
    _Float16* outh = Hbase + (size_t)z * 32 * 2048 * 64;

    __shared__ __align__(16) _Float16 As[2][128 * 32];
    __shared__ __align__(16) _Float16 Bs[2][128 * 32];
    const int tid = threadIdx.x;
    const int mBase = blockIdx.x * 128, nBase = blockIdx.y * 128;
    const int r0 = tid >> 2, c0 = (tid & 3) * 8;
    const float* gA = A + (size_t)(mBase + r0) * K + c0;
    const _Float16* gB = Bt + (size_t)(nBase + r0) * K + c0;
    const int lane = tid & 63, wid = tid >> 6;
    const int wm = (wid >> 1) * 64, wn = (wid & 1) * 64;
    const int fr = lane & 15, fg = lane >> 4;

    f32x4 acc[4][4] = {};
    float4 a00 = *(const float4*)(gA);
    float4 a01 = *(const float4*)(gA + 4);
    float4 a10 = *(const float4*)(gA + 64 * K);
    float4 a11 = *(const float4*)(gA + 64 * K + 4);
    half8 rb0 = *(const half8*)(gB);
    half8 rb1 = *(const half8*)(gB + 64 * K);
    for (int kt = 0; kt < K / 32; ++kt) {
        _Float16* as = &As[kt & 1][0];
        _Float16* bs = &Bs[kt & 1][0];
        *(half8*)&as[tid * 8] = cvt8(a00, a01);
        *(half8*)&as[tid * 8 + 2048] = cvt8(a10, a11);
        *(half8*)&bs[tid * 8] = rb0;
        *(half8*)&bs[tid * 8 + 2048] = rb1;
        __syncthreads();
        if (kt + 1 < K / 32) {
            const int k1 = (kt + 1) * 32;
            a00 = *(const float4*)(gA + k1);
            a01 = *(const float4*)(gA + k1 + 4);
            a10 = *(const float4*)(gA + 64 * K + k1);
            a11 = *(const float4*)(gA + 64 * K + k1 + 4);
            rb0 = *(const half8*)(gB + k1);
            rb1 = *(const half8*)(gB + 64 * K + k1);
        }
        half8 af[4], bfv[4];
#pragma unroll
        for (int i = 0; i < 4; ++i) af[i] = *(const half8*)&as[(wm + i * 16 + fr) * 32 + fg * 8];
#pragma unroll
        for (int i = 0; i < 4; ++i) bfv[i] = *(const half8*)&bs[(wn + i * 16 + fr) * 32 + fg * 8];
#pragma unroll
        for (int mi = 0; mi < 4; ++mi)
#pragma unroll
            for (int ni = 0; ni < 4; ++ni)
                acc[mi][ni] = MFMA16(af[mi], bfv[ni], acc[mi][ni]);
    }
    if (z == 2) {
        // V: write transposed [bh][d][s] directly (half4 at consecutive s)
#pragma unroll
        for (int mi = 0; mi < 4; ++mi)
#pragma unroll
            for (int ni = 0; ni < 4; ++ni) {
                const int row0 = mBase + wm + mi * 16 + fg * 4;   // s0 (4 consecutive)
                const int col = nBase + wn + ni * 16 + fr;        // h*64 + d
                const float bv_ = bias[col];
                const int b = row0 >> 11, s0 = row0 & 2047;
                const int h = col >> 6, d = col & 63;
                half4v o = { (_Float16)(acc[mi][ni][0] + bv_), (_Float16)(acc[mi][ni][1] + bv_),
                             (_Float16)(acc[mi][ni][2] + bv_), (_Float16)(acc[mi][ni][3] + bv_) };
                *(half4v*)&Vtp[((size_t)(b * 16 + h) * 64 + d) * 2048 + s0] = o;
            }
    } else {
#pragma unroll
        for (int mi = 0; mi < 4; ++mi)
#pragma unroll
            for (int ni = 0; ni < 4; ++ni)
#pragma unroll
                for (int j = 0; j < 4; ++j) {
                    const int row = mBase + wm + mi * 16 + fg * 4 + j;  // 0..4095
                    const int col = nBase + wn + ni * 16 + fr;          // 0..1023
                    const float v = acc[mi][ni][j] + bias[col];
                    const int b = row >> 11, s = row & 2047, h = col >> 6, d = col & 63;
                    outh[(((size_t)(b * 16 + h) * 2048) + s) * 64 + d] = (_Float16)v;
                }
    }
}

// ---------------------------------------------------------------------------
// Output projection GEMM: y = ctx @ Wo + bo + residual (fp32 out).
// 64x128 tile (512 blocks = 2 blocks/CU); dbuf LDS, 1 barrier/K-step.
// ---------------------------------------------------------------------------
__global__ __launch_bounds__(256) void gemm_out_kernel(
    const _Float16* __restrict__ A, const _Float16* __restrict__ Bt,
    const float* __restrict__ bias, const float* __restrict__ resid,
    float* __restrict__ outf) {
    constexpr int K = 1024;
    __shared__ __align__(16) _Float16 As[2][64 * 32];
    __shared__ __align__(16) _Float16 Bs[2][128 * 32];
    const int tid = threadIdx.x;
    const int mBase = blockIdx.x * 64, nBase = blockIdx.y * 128;
    const int r0 = tid >> 2, c0 = (tid & 3) * 8;   // r0: 0..63
    const _Float16* gA = A + (size_t)(mBase + r0) * K + c0;
    const _Float16* gB = Bt + (size_t)(nBase + r0) * K + c0;
    const int lane = tid & 63, wid = tid >> 6;
    const int wm = (wid >> 1) * 32, wn = (wid & 1) * 64;
    const int fr = lane & 15, fg = lane >> 4;

    f32x4 acc[2][4] = {};
    half8 ra0 = *(const half8*)(gA);
    half8 rb0 = *(const half8*)(gB);
    half8 rb1 = *(const half8*)(gB + 64 * K);
    for (int kt = 0; kt < K / 32; ++kt) {
        _Float16* as = &As[kt & 1][0];
        _Float16* bs = &Bs[kt & 1][0];
        *(half8*)&as[tid * 8] = ra0;
        *(half8*)&bs[tid * 8] = rb0;
        *(half8*)&bs[tid * 8 + 2048] = rb1;
        __syncthreads();
        if (kt + 1 < K / 32) {
            const int k1 = (kt + 1) * 32;
            ra0 = *(const half8*)(gA + k1);
            rb0 = *(const half8*)(gB + k1);
            rb1 = *(const half8*)(gB + 64 * K + k1);
        }
        half8 af[2], bfv[4];
#pragma unroll
        for (int i = 0; i < 2; ++i) af[i] = *(const half8*)&as[(wm + i * 16 + fr) * 32 + fg * 8];
#pragma unroll
        for (int i = 0; i < 4; ++i) bfv[i] = *(const half8*)&bs[(wn + i * 16 + fr) * 32 + fg * 8];
#pragma unroll
        for (int mi = 0; mi < 2; ++mi)
#pragma unroll
            for (int ni = 0; ni < 4; ++ni)
                acc[mi][ni] = MFMA16(af[mi], bfv[ni], acc[mi][ni]);
    }
#pragma unroll
    for (int mi = 0; mi < 2; ++mi)
#pragma unroll
        for (int ni = 0; ni < 4; ++ni)
#pragma unroll
            for (int j = 0; j < 4; ++j) {
                const int row = mBase + wm + mi * 16 + fg * 4 + j;
                const int col = nBase + wn + ni * 16 + fr;
                const size_t idx = (size_t)row * 1024 + col;
                outf[idx] = acc[mi][ni][j] + bias[col] + resid[idx];
            }
}

// ---------------------------------------------------------------------------
// Flash attention (r10, unchanged): plain __launch_bounds__(256), natural
// ~100 VGPR, zero spills, grid 1024 = 4 blocks/CU fully resident. 32 KB LDS;
// P overlays Ks per-wave quarters after the QK-reads-done barrier;
// multiplicative keep-mask; raw-score defer-max; cvt_pkrtz pack; setprio;
// permuted K rows.
// ---------------------------------------------------------------------------
__global__ __launch_bounds__(256) void attn_kernel(
    const _Float16* __restrict__ Qh, const _Float16* __restrict__ Kh,
    const _Float16* __restrict__ Vt, const _Float16* __restrict__ km,
    _Float16* __restrict__ ctx) {
    constexpr int S = 2048;
    constexpr int KT = 128;
    __shared__ __align__(16) _Float16 Ks[128][64];    // 16 KiB; P overlays per-wave quarters
    __shared__ __align__(16) _Float16 Vs[64][128];    // 16 KiB
    const int tid = threadIdx.x, lane = tid & 63, wid = tid >> 6;
    const int fr = lane & 15, fg = lane >> 4;
    const int bh = blockIdx.y;
    const int b = bh >> 4, h = bh & 15;
    const int q0 = blockIdx.x * 64 + wid * 16;
    const int q = q0 + fr;
    const _Float16* Qp = Qh + (size_t)bh * S * 64;
    const _Float16* Kp = Kh + (size_t)bh * S * 64;
    const _Float16* Vp = Vt + (size_t)bh * 64 * S;
    const _Float16* mrow = km + ((size_t)b * S + q) * S + fg * 32;

    // Q as B-fragment, pre-scaled into log2-domain: 0.125 * log2(e)
    half8 qf0 = *(const half8*)(Qp + (size_t)q * 64 + fg * 8);
    half8 qf1 = *(const half8*)(Qp + (size_t)q * 64 + 32 + fg * 8);
    const _Float16 QSC = (_Float16)0.18033688f;
#pragma unroll
    for (int i = 0; i < 8; ++i) { qf0[i] = qf0[i] * QSC; qf1[i] = qf1[i] * QSC; }
    half8 ones8;
#pragma unroll
    for (int i = 0; i < 8; ++i) ones8[i] = (_Float16)1.0f;

    // staging geometry (K rows permuted: position p holds true row (p&15)*8+(p>>4))
    const int kCol = (tid & 7) * 8;
    const int vCol = (tid & 15) * 8;
    int kTrue[4], kW[4], vRow[4], vW[4];
#pragma unroll
    for (int n = 0; n < 4; ++n) {
        const int p = (tid >> 3) + 32 * n;
        kTrue[n] = ((p & 15) << 3) | (p >> 4);
        kW[n] = p * 64 + (kCol ^ ((p & 7) << 3));
        const int d = (tid >> 4) + 16 * n;
        vRow[n] = d;
        vW[n] = d * 128 + (vCol ^ ((d & 15) << 3));
    }
    const int swzK = (fr & 7) << 3;
    const int swzV = fr << 3;

    f32x4 acc[4] = {};
    f32x4 accl = {};
    float m_r = -1e30f;
    const float TH = 11.5f;

    // prologue: tile 0 into regs
    half8 sK[4], sV[4], mcur[4], mnx[4];
#pragma unroll
    for (int n = 0; n < 4; ++n) {
        sK[n] = *(const half8*)(Kp + (size_t)kTrue[n] * 64 + kCol);
        sV[n] = *(const half8*)(Vp + (size_t)vRow[n] * S + vCol);
        mcur[n] = *(const half8*)(mrow + n * 8);
    }

    _Float16* Pw = &Ks[0][0] + wid * 2048;   // per-wave 32-row quarter (4 KB)

    for (int t = 0; t < 16; ++t) {
        __syncthreads();   // all waves done with prev tile (PV + P reads)
#pragma unroll
        for (int n = 0; n < 4; ++n) {
            *(half8*)&Ks[0][kW[n]] = sK[n];
            *(half8*)&Vs[0][vW[n]] = sV[n];
        }
        __syncthreads();   // buffer ready

        // issue next-tile global loads
        const int kn = (t < 15) ? (t + 1) * KT : t * KT;
#pragma unroll
        for (int n = 0; n < 4; ++n) {
            sK[n] = *(const half8*)(Kp + (size_t)(kn + kTrue[n]) * 64 + kCol);
            sV[n] = *(const half8*)(Vp + (size_t)vRow[n] * S + kn + vCol);
            mnx[n] = *(const half8*)(mrow + kn + n * 8);
        }

        // QK^T swapped: A = K positions, B = Q -> D[pos][q] (log2-domain)
        f32x4 tt[8];
        __builtin_amdgcn_s_setprio(1);
#pragma unroll
        for (int s = 0; s < 8; ++s) {
            const int p = s * 16 + fr;
            const half8 ka0 = *(const half8*)&Ks[0][p * 64 + ((fg * 8) ^ swzK)];
            const half8 ka1 = *(const half8*)&Ks[0][p * 64 + ((32 + fg * 8) ^ swzK)];
            f32x4 z = {};
            tt[s] = MFMA16(ka0, qf0, z);
            tt[s] = MFMA16(ka1, qf1, tt[s]);
        }
        __builtin_amdgcn_s_setprio(0);
        __syncthreads();   // all QK reads of Ks done before P overlay writes

        // raw-score max (upper bound incl. masked elems -> stability-safe)
        float pmax = -1e30f;
#pragma unroll
        for (int s = 0; s < 8; ++s)
#pragma unroll
            for (int j = 0; j < 4; ++j) pmax = fmaxf(pmax, tt[s][j]);
        if (__any(pmax > m_r + TH)) {
            pmax = fmaxf(pmax, __shfl_xor(pmax, 16));
            pmax = fmaxf(pmax, __shfl_xor(pmax, 32));
            const float mnew = fmaxf(m_r, pmax);
            const float scf = exp2f(m_r - mnew);
#pragma unroll
            for (int n = 0; n < 4; ++n)
#pragma unroll
                for (int j = 0; j < 4; ++j) acc[n][j] *= scf;
#pragma unroll
            for (int j = 0; j < 4; ++j) accl[j] *= scf;
            m_r = mnew;
        }
#pragma unroll
        for (int s = 0; s < 8; ++s)
#pragma unroll
            for (int j = 0; j < 4; ++j)
                tt[s][j] = exp2f(tt[s][j] - m_r);

        // pack P (cvt_pkrtz pairs along s), apply keep-mask, store to overlay
#pragma unroll
        for (int m = 0; m < 4; ++m) {
            half8 w;
#pragma unroll
            for (int a = 0; a < 4; ++a) {
                auto p2 = __builtin_amdgcn_cvt_pkrtz(tt[2 * a][m], tt[2 * a + 1][m]);
                w[2 * a] = (_Float16)p2[0]; w[2 * a + 1] = (_Float16)p2[1];
            }
            w *= mcur[m];   // v_pk_mul_f16: zero out masked keys
            *(half8*)&Pw[fr * 128 + ((fg * 32 + m * 8) ^ swzK)] = w;
        }

        // PV swapped: A = V rows (d), B = P^T -> D[d][q]; l via ones-MFMA
        __builtin_amdgcn_s_setprio(1);
#pragma unroll
        for (int c = 0; c < 4; ++c) {
            const half8 pa = *(const half8*)&Pw[fr * 128 + ((c * 32 + fg * 8) ^ swzK)];
            accl = MFMA16(ones8, pa, accl);
#pragma unroll
            for (int n = 0; n < 4; ++n) {
                const int d = n * 16 + fr;
                const half8 vb = *(const half8*)&Vs[0][d * 128 + ((c * 32 + fg * 8) ^ swzV)];
                acc[n] = MFMA16(vb, pa, acc[n]);
            }
        }
        __builtin_amdgcn_s_setprio(0);
#pragma unroll
        for (int n = 0; n < 4; ++n) mcur[n] = mnx[n];
    }

    const float inv = 1.0f / accl[0];
#pragma unroll
    for (int n = 0; n < 4; ++n) {
        half4v o = { (_Float16)(acc[n][0] * inv), (_Float16)(acc[n][1] * inv),
                     (_Float16)(acc[n][2] * inv), (_Float16)(acc[n][3] * inv) };
        *(half4v*)&ctx[((size_t)b * 2048 + q) * 1024 + h * 64 + n * 16 + fg * 4] = o;
    }
}

// LayerNorm over D=1024, one block per row
__global__ __launch_bounds__(256) void ln_kernel(
    const float* __restrict__ y, const float* __restrict__ gamma,
    const float* __restrict__ beta, float* __restrict__ out) {
    const int row = blockIdx.x, tid = threadIdx.x;
    const size_t base = (size_t)row * 1024 + tid * 4;
    const float4 v = *(const float4*)(y + base);
    float s = v.x + v.y + v.z + v.w;
    float ss = v.x * v.x + v.y * v.y + v.z * v.z + v.w * v.w;
#pragma unroll
    for (int o = 1; o < 64; o <<= 1) {
        s += __shfl_xor(s, o, 64);
        ss += __shfl_xor(ss, o, 64);
    }
    __shared__ float red[8];
    const int wid = tid >> 6;
    if ((tid & 63) == 0) { red[wid] = s; red[wid + 4] = ss; }
    __syncthreads();
    s = red[0] + red[1] + red[2] + red[3];
    ss = red[4] + red[5] + red[6] + red[7];
    const float mu = s * (1.0f / 1024.0f);
    const float var = ss * (1.0f / 1024.0f) - mu * mu;
    const float rstd = rsqrtf(var + 1e-5f);
    const float4 g = *(const float4*)(gamma + tid * 4);
    const float4 bt = *(const float4*)(beta + tid * 4);
    float4 o;
    o.x = (v.x - mu) * rstd * g.x + bt.x;
    o.y = (v.y - mu) * rstd * g.y + bt.y;
    o.z = (v.z - mu) * rstd * g.z + bt.z;
    o.w = (v.w - mu) * rstd * g.w + bt.w;
    *(float4*)(out + base) = o;
}

// ---------------------------------------------------------------------------
extern "C" void kernel_launch(void* const* d_in, const int* in_sizes, int n_in,
                              void* d_out, int out_size, void* d_ws, size_t ws_size,
                              hipStream_t stream) {
    (void)in_sizes; (void)n_in; (void)out_size; (void)ws_size;
    const float* q     = (const float*)d_in[0];
    const float* k     = (const float*)d_in[1];
    const float* v     = (const float*)d_in[2];
    const void*  mask  = d_in[3];
    const float* wq    = (const float*)d_in[4];
    const float* bq    = (const float*)d_in[5];
    const float* wk    = (const float*)d_in[6];
    const float* bk    = (const float*)d_in[7];
    const float* wv    = (const float*)d_in[8];
    const float* bv    = (const float*)d_in[9];
    const float* wo    = (const float*)d_in[10];
    const float* bo    = (const float*)d_in[11];
    const float* gamma = (const float*)d_in[12];
    const float* beta  = (const float*)d_in[13];

    char* ws = (char*)d_ws;
    constexpr size_t SZ_H = (size_t)4096 * 1024 * 2;   // 8 MiB (fp16 [4096][1024])
    constexpr size_t SZ_W = (size_t)1024 * 1024 * 2;   // 2 MiB (fp16 [1024][1024])
    size_t off = 256;
    _Float16* wt4 = (_Float16*)(ws + off); off += 4 * SZ_W;  // wq,wk,wv,wo transposed
    _Float16* scratchA = (_Float16*)(ws + off); off += SZ_H;  // ctx lives here
    _Float16* scratchB = (_Float16*)(ws + off); off += SZ_H;  // y (fp32, 2 slots)
    _Float16* scratchC = (_Float16*)(ws + off); off += SZ_H;
    _Float16* Qh  = (_Float16*)(ws + off); off += SZ_H;
    _Float16* Kh  = (_Float16*)(ws + off); off += SZ_H;
    _Float16* Vh  = (_Float16*)(ws + off); off += SZ_H;   // unused (kept for layout)
    _Float16* Vt  = (_Float16*)(ws + off); off += SZ_H;
    _Float16* km  = (_Float16*)(ws + off); off += (size_t)2 * 2048 * 2048 * 2;
    _Float16* wqt = wt4;
    _Float16* wot = wt4 + (size_t)3 * 1024 * 1024;
    _Float16* ctx = scratchA;
    float*    y   = (float*)scratchB;   // uses scratchB+scratchC (16 MiB)
    (void)Vh;

    prep_kernel<<<12288, 256, 0, stream>>>(wq, wk, wv, wo, wt4, mask, km);

    gemm_qkv_kernel<<<dim3(32, 8, 3), 256, 0, stream>>>(q, k, v, wqt, bq, bk, bv, Qh, Vt);
    attn_kernel<<<dim3(32, 32), 256, 0, stream>>>(Qh, Kh, Vt, km, ctx);
    gemm_out_kernel<<<dim3(64, 8), 256, 0, stream>>>(ctx, wot, bo, q, y);
    ln_kernel<<<4096, 256, 0, stream>>>(y, gamma, beta, (float*)d_out);
}

// Round 15
// 169.897 us; speedup vs baseline: 1.0125x; 1.0125x over previous
//
#include <hip/hip_runtime.h>
#include <hip/hip_fp16.h>
#include <math.h>

// ---------------------------------------------------------------------------
// Fused transformer block: QKV proj -> masked MHA -> out proj + residual -> LN
// B=2, S=2048, D=1024, H=16, hd=64.  All GEMM/attention compute in fp16 MFMA
// with fp32 accumulation; final output fp32.
// Best-of-session configuration (r13): prep fusion + dbuf GEMMs + 64x128
// gemm_out + r10 attn + standalone vtrans (r14 proved fusing V-transpose
// into the GEMM epilogue costs more in scattered stores than it saves).
// ---------------------------------------------------------------------------

typedef _Float16 half8 __attribute__((ext_vector_type(8)));
typedef _Float16 half4v __attribute__((ext_vector_type(4)));
typedef float f32x4 __attribute__((ext_vector_type(4)));

#define MFMA16(a, b, c) __builtin_amdgcn_mfma_f32_16x16x32_f16((a), (b), (c), 0, 0, 0)

static __device__ __forceinline__ half8 cvt8(float4 a, float4 b) {
    half8 h;
    h[0] = (_Float16)a.x; h[1] = (_Float16)a.y; h[2] = (_Float16)a.z; h[3] = (_Float16)a.w;
    h[4] = (_Float16)b.x; h[5] = (_Float16)b.y; h[6] = (_Float16)b.z; h[7] = (_Float16)b.w;
    return h;
}

// ---------------------------------------------------------------------------
// Unified prep kernel (one launch):
//   blocks [0, 4096):    W[k][n] fp32 -> Wt[n][k] fp16 for wq/wk/wv/wo
//   blocks [4096, 12288): mask -> multiplicative fp16 keep (1=attend, 0=mask)
//                         with per-block dtype self-detection (in-bounds for
//                         both dtypes; misdetect prob (1/8)^256 ~ 0).
// ---------------------------------------------------------------------------
__global__ __launch_bounds__(256) void prep_kernel(
    const float* __restrict__ W0, const float* __restrict__ W1,
    const float* __restrict__ W2, const float* __restrict__ W3,
    _Float16* __restrict__ WtBase,
    const void* __restrict__ mask, _Float16* __restrict__ km) {
    const int bid = blockIdx.x;
    const int tid = threadIdx.x;
    if (bid < 4096) {
        __shared__ float t[32][33];
        const int z = bid >> 10, tile = bid & 1023;
        const float* W = (z == 0) ? W0 : ((z == 1) ? W1 : ((z == 2) ? W2 : W3));
        _Float16* Wt = WtBase + (size_t)z * 1024 * 1024;
        const int tx = tid & 31, ty = tid >> 5;
        const int n0 = (tile & 31) * 32, k0 = (tile >> 5) * 32;
#pragma unroll
        for (int i = 0; i < 4; ++i)
            t[ty + i * 8][tx] = W[(size_t)(k0 + ty + i * 8) * 1024 + n0 + tx];
        __syncthreads();
#pragma unroll
        for (int i = 0; i < 4; ++i)
            Wt[(size_t)(n0 + ty + i * 8) * 1024 + k0 + tx] = (_Float16)t[tx][ty + i * 8];
    } else {
        __shared__ int any;
        const int b = bid - 4096;               // 0..8191, 1024 elements each
        const int i = (b * 256 + tid) * 4;      // element index
        const unsigned v = ((const unsigned*)mask)[b * 256 + tid];
        if (tid == 0) any = 0;
        __syncthreads();
        if (v > 1u) atomicOr(&any, 1);
        __syncthreads();
        const bool bytemode = (any != 0);
        int v0, v1, v2, v3;
        if (bytemode) {
            const unsigned int w = *(const unsigned int*)((const unsigned char*)mask + i);
            v0 = w & 0xff; v1 = (w >> 8) & 0xff; v2 = (w >> 16) & 0xff; v3 = (w >> 24) & 0xff;
        } else {
            const int4 w = *(const int4*)((const int*)mask + i);
            v0 = w.x; v1 = w.y; v2 = w.z; v3 = w.w;
        }
        const _Float16 ONE = (_Float16)1.0f;
        const _Float16 ZER = (_Float16)0.0f;
        half4v o = { v0 ? ZER : ONE, v1 ? ZER : ONE, v2 ? ZER : ONE, v3 ? ZER : ONE };
        *(half4v*)(km + i) = o;
    }
}

// Vh[bh][s][d] -> Vt[bh][d][s], 32x32 tiles (coalesced both ways via LDS;
// r14 proved this beats a scattered transposed GEMM epilogue)
__global__ void vtrans_kernel(const _Float16* __restrict__ Vh, _Float16* __restrict__ Vt) {
    __shared__ _Float16 t[32][33];
    const int tx = threadIdx.x, ty = threadIdx.y;
    const int d0 = blockIdx.x * 32, s0 = blockIdx.y * 32, bh = blockIdx.z;
    const _Float16* src = Vh + (size_t)bh * 2048 * 64;
    _Float16* dst = Vt + (size_t)bh * 64 * 2048;
#pragma unroll
    for (int i = 0; i < 4; ++i)
        t[ty + i * 8][tx] = src[(size_t)(s0 + ty + i * 8) * 64 + d0 + tx];
    __syncthreads();
#pragma unroll
    for (int i = 0; i < 4; ++i)
        dst[(size_t)(d0 + ty + i * 8) * 2048 + s0 + tx] = t[tx][ty + i * 8];
}

// ---------------------------------------------------------------------------
// QKV projection GEMM: double-buffered LDS, 1 barrier/K-step, fused
// fp32->fp16 cast on A. grid.z selects q/k/v. 128x128, BK=32, 4 waves.
// Coalesced head-layout epilogue [b,h,s,d] for all three outputs.
// ---------------------------------------------------------------------------
__global__ __launch_bounds__(256) void gemm_qkv_kernel(
    const float* __restrict__ Aq, const float* __restrict__ Ak, const float* __restrict__ Av,
    const _Float16* __restrict__ Btbase,
    const float* __restrict__ bq, const float* __restrict__ bk, const float* __restrict__ bv,
    _Float16* __restrict__ Hbase) {
    constexpr int K = 1024;
    const int z = blockIdx.z;
    const float* A = (z == 0) ? Aq : ((z == 1) ? Ak : Av);
    const _Float16* Bt = Btbase + (size_t)z * 1024 * 1024;
    const float* bias = (z == 0) ? bq : ((z == 1) ? bk : bv);
    _Float16* outh = Hbase + (size_t)z * 32 * 2048 * 64;

    __shared__ __align__(16) _Float16 As[2][128 * 32];
    __shared__ __align__(16) _Float16 Bs[2][128 * 32];
    const int tid = threadIdx.x;
    const int mBase = blockIdx.x * 128, nBase = blockIdx.y * 128;
    const int r0 = tid >> 2, c0 = (tid & 3) * 8;
    const float* gA = A + (size_t)(mBase + r0) * K + c0;
    const _Float16* gB = Bt + (size_t)(nBase + r0) * K + c0;
    const int lane = tid & 63, wid = tid >> 6;
    const int wm = (wid >> 1) * 64, wn = (wid & 1) * 64;
    const int fr = lane & 15, fg = lane >> 4;

    f32x4 acc[4][4] = {};
    float4 a00 = *(const float4*)(gA);
    float4 a01 = *(const float4*)(gA + 4);
    float4 a10 = *(const float4*)(gA + 64 * K);
    float4 a11 = *(const float4*)(gA + 64 * K + 4);
    half8 rb0 = *(const half8*)(gB);
    half8 rb1 = *(const half8*)(gB + 64 * K);
    for (int kt = 0; kt < K / 32; ++kt) {
        _Float16* as = &As[kt & 1][0];
        _Float16* bs = &Bs[kt & 1][0];
        *(half8*)&as[tid * 8] = cvt8(a00, a01);
        *(half8*)&as[tid * 8 + 2048] = cvt8(a10, a11);
        *(half8*)&bs[tid * 8] = rb0;
        *(half8*)&bs[tid * 8 + 2048] = rb1;
        __syncthreads();
        if (kt + 1 < K / 32) {
            const int k1 = (kt + 1) * 32;
            a00 = *(const float4*)(gA + k1);
            a01 = *(const float4*)(gA + k1 + 4);
            a10 = *(const float4*)(gA + 64 * K + k1);
            a11 = *(const float4*)(gA + 64 * K + k1 + 4);
            rb0 = *(const half8*)(gB + k1);
            rb1 = *(const half8*)(gB + 64 * K + k1);
        }
        half8 af[4], bfv[4];
#pragma unroll
        for (int i = 0; i < 4; ++i) af[i] = *(const half8*)&as[(wm + i * 16 + fr) * 32 + fg * 8];
#pragma unroll
        for (int i = 0; i < 4; ++i) bfv[i] = *(const half8*)&bs[(wn + i * 16 + fr) * 32 + fg * 8];
#pragma unroll
        for (int mi = 0; mi < 4; ++mi)
#pragma unroll
            for (int ni = 0; ni < 4; ++ni)
                acc[mi][ni] = MFMA16(af[mi], bfv[ni], acc[mi][ni]);
    }
#pragma unroll
    for (int mi = 0; mi < 4; ++mi)
#pragma unroll
        for (int ni = 0; ni < 4; ++ni)
#pragma unroll
            for (int j = 0; j < 4; ++j) {
                const int row = mBase + wm + mi * 16 + fg * 4 + j;  // 0..4095
                const int col = nBase + wn + ni * 16 + fr;          // 0..1023
                const float v = acc[mi][ni][j] + bias[col];
                const int b = row >> 11, s = row & 2047, h = col >> 6, d = col & 63;
                outh[(((size_t)(b * 16 + h) * 2048) + s) * 64 + d] = (_Float16)v;
            }
}

// ---------------------------------------------------------------------------
// Output projection GEMM: y = ctx @ Wo + bo + residual (fp32 out).
// 64x128 tile (512 blocks = 2 blocks/CU); dbuf LDS, 1 barrier/K-step.
// ---------------------------------------------------------------------------
__global__ __launch_bounds__(256) void gemm_out_kernel(
    const _Float16* __restrict__ A, const _Float16* __restrict__ Bt,
    const float* __restrict__ bias, const float* __restrict__ resid,
    float* __restrict__ outf) {
    constexpr int K = 1024;
    __shared__ __align__(16) _Float16 As[2][64 * 32];
    __shared__ __align__(16) _Float16 Bs[2][128 * 32];
    const int tid = threadIdx.x;
    const int mBase = blockIdx.x * 64, nBase = blockIdx.y * 128;
    const int r0 = tid >> 2, c0 = (tid & 3) * 8;   // r0: 0..63
    const _Float16* gA = A + (size_t)(mBase + r0) * K + c0;
    const _Float16* gB = Bt + (size_t)(nBase + r0) * K + c0;
    const int lane = tid & 63, wid = tid >> 6;
    const int wm = (wid >> 1) * 32, wn = (wid & 1) * 64;
    const int fr = lane & 15, fg = lane >> 4;

    f32x4 acc[2][4] = {};
    half8 ra0 = *(const half8*)(gA);
    half8 rb0 = *(const half8*)(gB);
    half8 rb1 = *(const half8*)(gB + 64 * K);
    for (int kt = 0; kt < K / 32; ++kt) {
        _Float16* as = &As[kt & 1][0];
        _Float16* bs = &Bs[kt & 1][0];
        *(half8*)&as[tid * 8] = ra0;
        *(half8*)&bs[tid * 8] = rb0;
        *(half8*)&bs[tid * 8 + 2048] = rb1;
        __syncthreads();
        if (kt + 1 < K / 32) {
            const int k1 = (kt + 1) * 32;
            ra0 = *(const half8*)(gA + k1);
            rb0 = *(const half8*)(gB + k1);
            rb1 = *(const half8*)(gB + 64 * K + k1);
        }
        half8 af[2], bfv[4];
#pragma unroll
        for (int i = 0; i < 2; ++i) af[i] = *(const half8*)&as[(wm + i * 16 + fr) * 32 + fg * 8];
#pragma unroll
        for (int i = 0; i < 4; ++i) bfv[i] = *(const half8*)&bs[(wn + i * 16 + fr) * 32 + fg * 8];
#pragma unroll
        for (int mi = 0; mi < 2; ++mi)
#pragma unroll
            for (int ni = 0; ni < 4; ++ni)
                acc[mi][ni] = MFMA16(af[mi], bfv[ni], acc[mi][ni]);
    }
#pragma unroll
    for (int mi = 0; mi < 2; ++mi)
#pragma unroll
        for (int ni = 0; ni < 4; ++ni)
#pragma unroll
            for (int j = 0; j < 4; ++j) {
                const int row = mBase + wm + mi * 16 + fg * 4 + j;
                const int col = nBase + wn + ni * 16 + fr;
                const size_t idx = (size_t)row * 1024 + col;
                outf[idx] = acc[mi][ni][j] + bias[col] + resid[idx];
            }
}

// ---------------------------------------------------------------------------
// Flash attention (r10): plain __launch_bounds__(256), natural ~100 VGPR,
// zero spills, grid 1024 = 4 blocks/CU fully resident. 32 KB LDS; P overlays
// Ks per-wave quarters after the QK-reads-done barrier; multiplicative
// keep-mask; raw-score defer-max; cvt_pkrtz pack; setprio; permuted K rows.
// ---------------------------------------------------------------------------
__global__ __launch_bounds__(256) void attn_kernel(
    const _Float16* __restrict__ Qh, const _Float16* __restrict__ Kh,
    const _Float16* __restrict__ Vt, const _Float16* __restrict__ km,
    _Float16* __restrict__ ctx) {
    constexpr int S = 2048;
    constexpr int KT = 128;
    __shared__ __align__(16) _Float16 Ks[128][64];    // 16 KiB; P overlays per-wave quarters
    __shared__ __align__(16) _Float16 Vs[64][128];    // 16 KiB
    const int tid = threadIdx.x, lane = tid & 63, wid = tid >> 6;
    const int fr = lane & 15, fg = lane >> 4;
    const int bh = blockIdx.y;
    const int b = bh >> 4, h = bh & 15;
    const int q0 = blockIdx.x * 64 + wid * 16;
    const int q = q0 + fr;
    const _Float16* Qp = Qh + (size_t)bh * S * 64;
    const _Float16* Kp = Kh + (size_t)bh * S * 64;
    const _Float16* Vp = Vt + (size_t)bh * 64 * S;
    const _Float16* mrow = km + ((size_t)b * S + q) * S + fg * 32;

    // Q as B-fragment, pre-scaled into log2-domain: 0.125 * log2(e)
    half8 qf0 = *(const half8*)(Qp + (size_t)q * 64 + fg * 8);
    half8 qf1 = *(const half8*)(Qp + (size_t)q * 64 + 32 + fg * 8);
    const _Float16 QSC = (_Float16)0.18033688f;
#pragma unroll
    for (int i = 0; i < 8; ++i) { qf0[i] = qf0[i] * QSC; qf1[i] = qf1[i] * QSC; }
    half8 ones8;
#pragma unroll
    for (int i = 0; i < 8; ++i) ones8[i] = (_Float16)1.0f;

    // staging geometry (K rows permuted: position p holds true row (p&15)*8+(p>>4))
    const int kCol = (tid & 7) * 8;
    const int vCol = (tid & 15) * 8;
    int kTrue[4], kW[4], vRow[4], vW[4];
#pragma unroll
    for (int n = 0; n < 4; ++n) {
        const int p = (tid >> 3) + 32 * n;
        kTrue[n] = ((p & 15) << 3) | (p >> 4);
        kW[n] = p * 64 + (kCol ^ ((p & 7) << 3));
        const int d = (tid >> 4) + 16 * n;
        vRow[n] = d;
        vW[n] = d * 128 + (vCol ^ ((d & 15) << 3));
    }
    const int swzK = (fr & 7) << 3;
    const int swzV = fr << 3;

    f32x4 acc[4] = {};
    f32x4 accl = {};
    float m_r = -1e30f;
    const float TH = 11.5f;

    // prologue: tile 0 into regs
    half8 sK[4], sV[4], mcur[4], mnx[4];
#pragma unroll
    for (int n = 0; n < 4; ++n) {
        sK[n] = *(const half8*)(Kp + (size_t)kTrue[n] * 64 + kCol);
        sV[n] = *(const half8*)(Vp + (size_t)vRow[n] * S + vCol);
        mcur[n] = *(const half8*)(mrow + n * 8);
    }

    _Float16* Pw = &Ks[0][0] + wid * 2048;   // per-wave 32-row quarter (4 KB)

    for (int t = 0; t < 16; ++t) {
        __syncthreads();   // all waves done with prev tile (PV + P reads)
#pragma unroll
        for (int n = 0; n < 4; ++n) {
            *(half8*)&Ks[0][kW[n]] = sK[n];
            *(half8*)&Vs[0][vW[n]] = sV[n];
        }
        __syncthreads();   // buffer ready

        // issue next-tile global loads
        const int kn = (t < 15) ? (t + 1) * KT : t * KT;
#pragma unroll
        for (int n = 0; n < 4; ++n) {
            sK[n] = *(const half8*)(Kp + (size_t)(kn + kTrue[n]) * 64 + kCol);
            sV[n] = *(const half8*)(Vp + (size_t)vRow[n] * S + kn + vCol);
            mnx[n] = *(const half8*)(mrow + kn + n * 8);
        }

        // QK^T swapped: A = K positions, B = Q -> D[pos][q] (log2-domain)
        f32x4 tt[8];
        __builtin_amdgcn_s_setprio(1);
#pragma unroll
        for (int s = 0; s < 8; ++s) {
            const int p = s * 16 + fr;
            const half8 ka0 = *(const half8*)&Ks[0][p * 64 + ((fg * 8) ^ swzK)];
            const half8 ka1 = *(const half8*)&Ks[0][p * 64 + ((32 + fg * 8) ^ swzK)];
            f32x4 z = {};
            tt[s] = MFMA16(ka0, qf0, z);
            tt[s] = MFMA16(ka1, qf1, tt[s]);
        }
        __builtin_amdgcn_s_setprio(0);
        __syncthreads();   // all QK reads of Ks done before P overlay writes

        // raw-score max (upper bound incl. masked elems -> stability-safe)
        float pmax = -1e30f;
#pragma unroll
        for (int s = 0; s < 8; ++s)
#pragma unroll
            for (int j = 0; j < 4; ++j) pmax = fmaxf(pmax, tt[s][j]);
        if (__any(pmax > m_r + TH)) {
            pmax = fmaxf(pmax, __shfl_xor(pmax, 16));
            pmax = fmaxf(pmax, __shfl_xor(pmax, 32));
            const float mnew = fmaxf(m_r, pmax);
            const float scf = exp2f(m_r - mnew);
#pragma unroll
            for (int n = 0; n < 4; ++n)
#pragma unroll
                for (int j = 0; j < 4; ++j) acc[n][j] *= scf;
#pragma unroll
            for (int j = 0; j < 4; ++j) accl[j] *= scf;
            m_r = mnew;
        }
#pragma unroll
        for (int s = 0; s < 8; ++s)
#pragma unroll
            for (int j = 0; j < 4; ++j)
                tt[s][j] = exp2f(tt[s][j] - m_r);

        // pack P (cvt_pkrtz pairs along s), apply keep-mask, store to overlay
#pragma unroll
        for (int m = 0; m < 4; ++m) {
            half8 w;
#pragma unroll
            for (int a = 0; a < 4; ++a) {
                auto p2 = __builtin_amdgcn_cvt_pkrtz(tt[2 * a][m], tt[2 * a + 1][m]);
                w[2 * a] = (_Float16)p2[0]; w[2 * a + 1] = (_Float16)p2[1];
            }
            w *= mcur[m];   // v_pk_mul_f16: zero out masked keys
            *(half8*)&Pw[fr * 128 + ((fg * 32 + m * 8) ^ swzK)] = w;
        }

        // PV swapped: A = V rows (d), B = P^T -> D[d][q]; l via ones-MFMA
        __builtin_amdgcn_s_setprio(1);
#pragma unroll
        for (int c = 0; c < 4; ++c) {
            const half8 pa = *(const half8*)&Pw[fr * 128 + ((c * 32 + fg * 8) ^ swzK)];
            accl = MFMA16(ones8, pa, accl);
#pragma unroll
            for (int n = 0; n < 4; ++n) {
                const int d = n * 16 + fr;
                const half8 vb = *(const half8*)&Vs[0][d * 128 + ((c * 32 + fg * 8) ^ swzV)];
                acc[n] = MFMA16(vb, pa, acc[n]);
            }
        }
        __builtin_amdgcn_s_setprio(0);
#pragma unroll
        for (int n = 0; n < 4; ++n) mcur[n] = mnx[n];
    }

    const float inv = 1.0f / accl[0];
#pragma unroll
    for (int n = 0; n < 4; ++n) {
        half4v o = { (_Float16)(acc[n][0] * inv), (_Float16)(acc[n][1] * inv),
                     (_Float16)(acc[n][2] * inv), (_Float16)(acc[n][3] * inv) };
        *(half4v*)&ctx[((size_t)b * 2048 + q) * 1024 + h * 64 + n * 16 + fg * 4] = o;
    }
}

// LayerNorm over D=1024, one block per row
__global__ __launch_bounds__(256) void ln_kernel(
    const float* __restrict__ y, const float* __restrict__ gamma,
    const float* __restrict__ beta, float* __restrict__ out) {
    const int row = blockIdx.x, tid = threadIdx.x;
    const size_t base = (size_t)row * 1024 + tid * 4;
    const float4 v = *(const float4*)(y + base);
    float s = v.x + v.y + v.z + v.w;
    float ss = v.x * v.x + v.y * v.y + v.z * v.z + v.w * v.w;
#pragma unroll
    for (int o = 1; o < 64; o <<= 1) {
        s += __shfl_xor(s, o, 64);
        ss += __shfl_xor(ss, o, 64);
    }
    __shared__ float red[8];
    const int wid = tid >> 6;
    if ((tid & 63) == 0) { red[wid] = s; red[wid + 4] = ss; }
    __syncthreads();
    s = red[0] + red[1] + red[2] + red[3];
    ss = red[4] + red[5] + red[6] + red[7];
    const float mu = s * (1.0f / 1024.0f);
    const float var = ss * (1.0f / 1024.0f) - mu * mu;
    const float rstd = rsqrtf(var + 1e-5f);
    const float4 g = *(const float4*)(gamma + tid * 4);
    const float4 bt = *(const float4*)(beta + tid * 4);
    float4 o;
    o.x = (v.x - mu) * rstd * g.x + bt.x;
    o.y = (v.y - mu) * rstd * g.y + bt.y;
    o.z = (v.z - mu) * rstd * g.z + bt.z;
    o.w = (v.w - mu) * rstd * g.w + bt.w;
    *(float4*)(out + base) = o;
}

// ---------------------------------------------------------------------------
extern "C" void kernel_launch(void* const* d_in, const int* in_sizes, int n_in,
                              void* d_out, int out_size, void* d_ws, size_t ws_size,
                              hipStream_t stream) {
    (void)in_sizes; (void)n_in; (void)out_size; (void)ws_size;
    const float* q     = (const float*)d_in[0];
    const float* k     = (const float*)d_in[1];
    const float* v     = (const float*)d_in[2];
    const void*  mask  = d_in[3];
    const float* wq    = (const float*)d_in[4];
    const float* bq    = (const float*)d_in[5];
    const float* wk    = (const float*)d_in[6];
    const float* bk    = (const float*)d_in[7];
    const float* wv    = (const float*)d_in[8];
    const float* bv    = (const float*)d_in[9];
    const float* wo    = (const float*)d_in[10];
    const float* bo    = (const float*)d_in[11];
    const float* gamma = (const float*)d_in[12];
    const float* beta  = (const float*)d_in[13];

    char* ws = (char*)d_ws;
    constexpr size_t SZ_H = (size_t)4096 * 1024 * 2;   // 8 MiB (fp16 [4096][1024])
    constexpr size_t SZ_W = (size_t)1024 * 1024 * 2;   // 2 MiB (fp16 [1024][1024])
    size_t off = 256;
    _Float16* wt4 = (_Float16*)(ws + off); off += 4 * SZ_W;  // wq,wk,wv,wo transposed
    _Float16* scratchA = (_Float16*)(ws + off); off += SZ_H;  // ctx lives here
    _Float16* scratchB = (_Float16*)(ws + off); off += SZ_H;  // y (fp32, 2 slots)
    _Float16* scratchC = (_Float16*)(ws + off); off += SZ_H;
    _Float16* Qh  = (_Float16*)(ws + off); off += SZ_H;
    _Float16* Kh  = (_Float16*)(ws + off); off += SZ_H;
    _Float16* Vh  = (_Float16*)(ws + off); off += SZ_H;
    _Float16* Vt  = (_Float16*)(ws + off); off += SZ_H;
    _Float16* km  = (_Float16*)(ws + off); off += (size_t)2 * 2048 * 2048 * 2;
    _Float16* wqt = wt4;
    _Float16* wot = wt4 + (size_t)3 * 1024 * 1024;
    _Float16* ctx = scratchA;
    float*    y   = (float*)scratchB;   // uses scratchB+scratchC (16 MiB)

    prep_kernel<<<12288, 256, 0, stream>>>(wq, wk, wv, wo, wt4, mask, km);

    gemm_qkv_kernel<<<dim3(32, 8, 3), 256, 0, stream>>>(q, k, v, wqt, bq, bk, bv, Qh);
    dim3 tb(32, 8);
    vtrans_kernel<<<dim3(2, 64, 32), tb, 0, stream>>>(Vh, Vt);
    attn_kernel<<<dim3(32, 32), 256, 0, stream>>>(Qh, Kh, Vt, km, ctx);
    gemm_out_kernel<<<dim3(64, 8), 256, 0, stream>>>(ctx, wot, bo, q, y);
    ln_kernel<<<4096, 256, 0, stream>>>(y, gamma, beta, (float*)d_out);
}

// Round 16
// 167.441 us; speedup vs baseline: 1.0273x; 1.0147x over previous
//
#include <hip/hip_runtime.h>
#include <hip/hip_fp16.h>
#include <math.h>

// ---------------------------------------------------------------------------
// Fused transformer block: QKV proj -> masked MHA -> out proj + residual -> LN
// B=2, S=2048, D=1024, H=16, hd=64.  All GEMM/attention compute in fp16 MFMA
// with fp32 accumulation; final output fp32.
// r16 = r13/r15 best config + fp16 intermediate y (halves y traffic; error
// budget: fp16 y adds ~0.002 abs after LN vs threshold 0.099).
// ---------------------------------------------------------------------------

typedef _Float16 half8 __attribute__((ext_vector_type(8)));
typedef _Float16 half4v __attribute__((ext_vector_type(4)));
typedef float f32x4 __attribute__((ext_vector_type(4)));

#define MFMA16(a, b, c) __builtin_amdgcn_mfma_f32_16x16x32_f16((a), (b), (c), 0, 0, 0)

static __device__ __forceinline__ half8 cvt8(float4 a, float4 b) {
    half8 h;
    h[0] = (_Float16)a.x; h[1] = (_Float16)a.y; h[2] = (_Float16)a.z; h[3] = (_Float16)a.w;
    h[4] = (_Float16)b.x; h[5] = (_Float16)b.y; h[6] = (_Float16)b.z; h[7] = (_Float16)b.w;
    return h;
}

// ---------------------------------------------------------------------------
// Unified prep kernel (one launch):
//   blocks [0, 4096):    W[k][n] fp32 -> Wt[n][k] fp16 for wq/wk/wv/wo
//   blocks [4096, 12288): mask -> multiplicative fp16 keep (1=attend, 0=mask)
//                         with per-block dtype self-detection (in-bounds for
//                         both dtypes; misdetect prob (1/8)^256 ~ 0).
// ---------------------------------------------------------------------------
__global__ __launch_bounds__(256) void prep_kernel(
    const float* __restrict__ W0, const float* __restrict__ W1,
    const float* __restrict__ W2, const float* __restrict__ W3,
    _Float16* __restrict__ WtBase,
    const void* __restrict__ mask, _Float16* __restrict__ km) {
    const int bid = blockIdx.x;
    const int tid = threadIdx.x;
    if (bid < 4096) {
        __shared__ float t[32][33];
        const int z = bid >> 10, tile = bid & 1023;
        const float* W = (z == 0) ? W0 : ((z == 1) ? W1 : ((z == 2) ? W2 : W3));
        _Float16* Wt = WtBase + (size_t)z * 1024 * 1024;
        const int tx = tid & 31, ty = tid >> 5;
        const int n0 = (tile & 31) * 32, k0 = (tile >> 5) * 32;
#pragma unroll
        for (int i = 0; i < 4; ++i)
            t[ty + i * 8][tx] = W[(size_t)(k0 + ty + i * 8) * 1024 + n0 + tx];
        __syncthreads();
#pragma unroll
        for (int i = 0; i < 4; ++i)
            Wt[(size_t)(n0 + ty + i * 8) * 1024 + k0 + tx] = (_Float16)t[tx][ty + i * 8];
    } else {
        __shared__ int any;
        const int b = bid - 4096;               // 0..8191, 1024 elements each
        const int i = (b * 256 + tid) * 4;      // element index
        const unsigned v = ((const unsigned*)mask)[b * 256 + tid];
        if (tid == 0) any = 0;
        __syncthreads();
        if (v > 1u) atomicOr(&any, 1);
        __syncthreads();
        const bool bytemode = (any != 0);
        int v0, v1, v2, v3;
        if (bytemode) {
            const unsigned int w = *(const unsigned int*)((const unsigned char*)mask + i);
            v0 = w & 0xff; v1 = (w >> 8) & 0xff; v2 = (w >> 16) & 0xff; v3 = (w >> 24) & 0xff;
        } else {
            const int4 w = *(const int4*)((const int*)mask + i);
            v0 = w.x; v1 = w.y; v2 = w.z; v3 = w.w;
        }
        const _Float16 ONE = (_Float16)1.0f;
        const _Float16 ZER = (_Float16)0.0f;
        half4v o = { v0 ? ZER : ONE, v1 ? ZER : ONE, v2 ? ZER : ONE, v3 ? ZER : ONE };
        *(half4v*)(km + i) = o;
    }
}

// Vh[bh][s][d] -> Vt[bh][d][s], 32x32 tiles (coalesced both ways via LDS)
__global__ void vtrans_kernel(const _Float16* __restrict__ Vh, _Float16* __restrict__ Vt) {
    __shared__ _Float16 t[32][33];
    const int tx = threadIdx.x, ty = threadIdx.y;
    const int d0 = blockIdx.x * 32, s0 = blockIdx.y * 32, bh = blockIdx.z;
    const _Float16* src = Vh + (size_t)bh * 2048 * 64;
    _Float16* dst = Vt + (size_t)bh * 64 * 2048;
#pragma unroll
    for (int i = 0; i < 4; ++i)
        t[ty + i * 8][tx] = src[(size_t)(s0 + ty + i * 8) * 64 + d0 + tx];
    __syncthreads();
#pragma unroll
    for (int i = 0; i < 4; ++i)
        dst[(size_t)(d0 + ty + i * 8) * 2048 + s0 + tx] = t[tx][ty + i * 8];
}

// ---------------------------------------------------------------------------
// QKV projection GEMM: double-buffered LDS, 1 barrier/K-step, fused
// fp32->fp16 cast on A. grid.z selects q/k/v. 128x128, BK=32, 4 waves.
// ---------------------------------------------------------------------------
__global__ __launch_bounds__(256) void gemm_qkv_kernel(
    const float* __restrict__ Aq, const float* __restrict__ Ak, const float* __restrict__ Av,
    const _Float16* __restrict__ Btbase,
    const float* __restrict__ bq, const float* __restrict__ bk, const float* __restrict__ bv,
    _Float16* __restrict__ Hbase) {
    constexpr int K = 1024;
    const int z = blockIdx.z;
    const float* A = (z == 0) ? Aq : ((z == 1) ? Ak : Av);
    const _Float16* Bt = Btbase + (size_t)z * 1024 * 1024;
    const float* bias = (z == 0) ? bq : ((z == 1) ? bk : bv);
    _Float16* outh = Hbase + (size_t)z * 32 * 2048 * 64;

    __shared__ __align__(16) _Float16 As[2][128 * 32];
    __shared__ __align__(16) _Float16 Bs[2][128 * 32];
    const int tid = threadIdx.x;
    const int mBase = blockIdx.x * 128, nBase = blockIdx.y * 128;
    const int r0 = tid >> 2, c0 = (tid & 3) * 8;
    const float* gA = A + (size_t)(mBase + r0) * K + c0;
    const _Float16* gB = Bt + (size_t)(nBase + r0) * K + c0;
    const int lane = tid & 63, wid = tid >> 6;
    const int wm = (wid >> 1) * 64, wn = (wid & 1) * 64;
    const int fr = lane & 15, fg = lane >> 4;

    f32x4 acc[4][4] = {};
    float4 a00 = *(const float4*)(gA);
    float4 a01 = *(const float4*)(gA + 4);
    float4 a10 = *(const float4*)(gA + 64 * K);
    float4 a11 = *(const float4*)(gA + 64 * K + 4);
    half8 rb0 = *(const half8*)(gB);
    half8 rb1 = *(const half8*)(gB + 64 * K);
    for (int kt = 0; kt < K / 32; ++kt) {
        _Float16* as = &As[kt & 1][0];
        _Float16* bs = &Bs[kt & 1][0];
        *(half8*)&as[tid * 8] = cvt8(a00, a01);
        *(half8*)&as[tid * 8 + 2048] = cvt8(a10, a11);
        *(half8*)&bs[tid * 8] = rb0;
        *(half8*)&bs[tid * 8 + 2048] = rb1;
        __syncthreads();
        if (kt + 1 < K / 32) {
            const int k1 = (kt + 1) * 32;
            a00 = *(const float4*)(gA + k1);
            a01 = *(const float4*)(gA + k1 + 4);
            a10 = *(const float4*)(gA + 64 * K + k1);
            a11 = *(const float4*)(gA + 64 * K + k1 + 4);
            rb0 = *(const half8*)(gB + k1);
            rb1 = *(const half8*)(gB + 64 * K + k1);
        }
        half8 af[4], bfv[4];
#pragma unroll
        for (int i = 0; i < 4; ++i) af[i] = *(const half8*)&as[(wm + i * 16 + fr) * 32 + fg * 8];
#pragma unroll
        for (int i = 0; i < 4; ++i) bfv[i] = *(const half8*)&bs[(wn + i * 16 + fr) * 32 + fg * 8];
#pragma unroll
        for (int mi = 0; mi < 4; ++mi)
#pragma unroll
            for (int ni = 0; ni < 4; ++ni)
                acc[mi][ni] = MFMA16(af[mi], bfv[ni], acc[mi][ni]);
    }
#pragma unroll
    for (int mi = 0; mi < 4; ++mi)
#pragma unroll
        for (int ni = 0; ni < 4; ++ni)
#pragma unroll
            for (int j = 0; j < 4; ++j) {
                const int row = mBase + wm + mi * 16 + fg * 4 + j;  // 0..4095
                const int col = nBase + wn + ni * 16 + fr;          // 0..1023
                const float v = acc[mi][ni][j] + bias[col];
                const int b = row >> 11, s = row & 2047, h = col >> 6, d = col & 63;
                outh[(((size_t)(b * 16 + h) * 2048) + s) * 64 + d] = (_Float16)v;
            }
}

// ---------------------------------------------------------------------------
// Output projection GEMM: y = ctx @ Wo + bo + residual -> fp16 y.
// 64x128 tile (512 blocks = 2 blocks/CU); dbuf LDS, 1 barrier/K-step.
// ---------------------------------------------------------------------------
__global__ __launch_bounds__(256) void gemm_out_kernel(
    const _Float16* __restrict__ A, const _Float16* __restrict__ Bt,
    const float* __restrict__ bias, const float* __restrict__ resid,
    _Float16* __restrict__ outh) {
    constexpr int K = 1024;
    __shared__ __align__(16) _Float16 As[2][64 * 32];
    __shared__ __align__(16) _Float16 Bs[2][128 * 32];
    const int tid = threadIdx.x;
    const int mBase = blockIdx.x * 64, nBase = blockIdx.y * 128;
    const int r0 = tid >> 2, c0 = (tid & 3) * 8;   // r0: 0..63
    const _Float16* gA = A + (size_t)(mBase + r0) * K + c0;
    const _Float16* gB = Bt + (size_t)(nBase + r0) * K + c0;
    const int lane = tid & 63, wid = tid >> 6;
    const int wm = (wid >> 1) * 32, wn = (wid & 1) * 64;
    const int fr = lane & 15, fg = lane >> 4;

    f32x4 acc[2][4] = {};
    half8 ra0 = *(const half8*)(gA);
    half8 rb0 = *(const half8*)(gB);
    half8 rb1 = *(const half8*)(gB + 64 * K);
    for (int kt = 0; kt < K / 32; ++kt) {
        _Float16* as = &As[kt & 1][0];
        _Float16* bs = &Bs[kt & 1][0];
        *(half8*)&as[tid * 8] = ra0;
        *(half8*)&bs[tid * 8] = rb0;
        *(half8*)&bs[tid * 8 + 2048] = rb1;
        __syncthreads();
        if (kt + 1 < K / 32) {
            const int k1 = (kt + 1) * 32;
            ra0 = *(const half8*)(gA + k1);
            rb0 = *(const half8*)(gB + k1);
            rb1 = *(const half8*)(gB + 64 * K + k1);
        }
        half8 af[2], bfv[4];
#pragma unroll
        for (int i = 0; i < 2; ++i) af[i] = *(const half8*)&as[(wm + i * 16 + fr) * 32 + fg * 8];
#pragma unroll
        for (int i = 0; i < 4; ++i) bfv[i] = *(const half8*)&bs[(wn + i * 16 + fr) * 32 + fg * 8];
#pragma unroll
        for (int mi = 0; mi < 2; ++mi)
#pragma unroll
            for (int ni = 0; ni < 4; ++ni)
                acc[mi][ni] = MFMA16(af[mi], bfv[ni], acc[mi][ni]);
    }
#pragma unroll
    for (int mi = 0; mi < 2; ++mi)
#pragma unroll
        for (int ni = 0; ni < 4; ++ni)
#pragma unroll
            for (int j = 0; j < 4; ++j) {
                const int row = mBase + wm + mi * 16 + fg * 4 + j;
                const int col = nBase + wn + ni * 16 + fr;
                const size_t idx = (size_t)row * 1024 + col;
                outh[idx] = (_Float16)(acc[mi][ni][j] + bias[col] + resid[idx]);
            }
}

// ---------------------------------------------------------------------------
// Flash attention (r10): plain __launch_bounds__(256), natural ~100 VGPR,
// zero spills, grid 1024 = 4 blocks/CU fully resident. 32 KB LDS; P overlays
// Ks per-wave quarters after the QK-reads-done barrier; multiplicative
// keep-mask; raw-score defer-max; cvt_pkrtz pack; setprio; permuted K rows.
// ---------------------------------------------------------------------------
__global__ __launch_bounds__(256) void attn_kernel(
    const _Float16* __restrict__ Qh, const _Float16* __restrict__ Kh,
    const _Float16* __restrict__ Vt, const _Float16* __restrict__ km,
    _Float16* __restrict__ ctx) {
    constexpr int S = 2048;
    constexpr int KT = 128;
    __shared__ __align__(16) _Float16 Ks[128][64];    // 16 KiB; P overlays per-wave quarters
    __shared__ __align__(16) _Float16 Vs[64][128];    // 16 KiB
    const int tid = threadIdx.x, lane = tid & 63, wid = tid >> 6;
    const int fr = lane & 15, fg = lane >> 4;
    const int bh = blockIdx.y;
    const int b = bh >> 4, h = bh & 15;
    const int q0 = blockIdx.x * 64 + wid * 16;
    const int q = q0 + fr;
    const _Float16* Qp = Qh + (size_t)bh * S * 64;
    const _Float16* Kp = Kh + (size_t)bh * S * 64;
    const _Float16* Vp = Vt + (size_t)bh * 64 * S;
    const _Float16* mrow = km + ((size_t)b * S + q) * S + fg * 32;

    // Q as B-fragment, pre-scaled into log2-domain: 0.125 * log2(e)
    half8 qf0 = *(const half8*)(Qp + (size_t)q * 64 + fg * 8);
    half8 qf1 = *(const half8*)(Qp + (size_t)q * 64 + 32 + fg * 8);
    const _Float16 QSC = (_Float16)0.18033688f;
#pragma unroll
    for (int i = 0; i < 8; ++i) { qf0[i] = qf0[i] * QSC; qf1[i] = qf1[i] * QSC; }
    half8 ones8;
#pragma unroll
    for (int i = 0; i < 8; ++i) ones8[i] = (_Float16)1.0f;

    // staging geometry (K rows permuted: position p holds true row (p&15)*8+(p>>4))
    const int kCol = (tid & 7) * 8;
    const int vCol = (tid & 15) * 8;
    int kTrue[4], kW[4], vRow[4], vW[4];
#pragma unroll
    for (int n = 0; n < 4; ++n) {
        const int p = (tid >> 3) + 32 * n;
        kTrue[n] = ((p & 15) << 3) | (p >> 4);
        kW[n] = p * 64 + (kCol ^ ((p & 7) << 3));
        const int d = (tid >> 4) + 16 * n;
        vRow[n] = d;
        vW[n] = d * 128 + (vCol ^ ((d & 15) << 3));
    }
    const int swzK = (fr & 7) << 3;
    const int swzV = fr << 3;

    f32x4 acc[4] = {};
    f32x4 accl = {};
    float m_r = -1e30f;
    const float TH = 11.5f;

    // prologue: tile 0 into regs
    half8 sK[4], sV[4], mcur[4], mnx[4];
#pragma unroll
    for (int n = 0; n < 4; ++n) {
        sK[n] = *(const half8*)(Kp + (size_t)kTrue[n] * 64 + kCol);
        sV[n] = *(const half8*)(Vp + (size_t)vRow[n] * S + vCol);
        mcur[n] = *(const half8*)(mrow + n * 8);
    }

    _Float16* Pw = &Ks[0][0] + wid * 2048;   // per-wave 32-row quarter (4 KB)

    for (int t = 0; t < 16; ++t) {
        __syncthreads();   // all waves done with prev tile (PV + P reads)
#pragma unroll
        for (int n = 0; n < 4; ++n) {
            *(half8*)&Ks[0][kW[n]] = sK[n];
            *(half8*)&Vs[0][vW[n]] = sV[n];
        }
        __syncthreads();   // buffer ready

        // issue next-tile global loads
        const int kn = (t < 15) ? (t + 1) * KT : t * KT;
#pragma unroll
        for (int n = 0; n < 4; ++n) {
            sK[n] = *(const half8*)(Kp + (size_t)(kn + kTrue[n]) * 64 + kCol);
            sV[n] = *(const half8*)(Vp + (size_t)vRow[n] * S + kn + vCol);
            mnx[n] = *(const half8*)(mrow + kn + n * 8);
        }

        // QK^T swapped: A = K positions, B = Q -> D[pos][q] (log2-domain)
        f32x4 tt[8];
        __builtin_amdgcn_s_setprio(1);
#pragma unroll
        for (int s = 0; s < 8; ++s) {
            const int p = s * 16 + fr;
            const half8 ka0 = *(const half8*)&Ks[0][p * 64 + ((fg * 8) ^ swzK)];
            const half8 ka1 = *(const half8*)&Ks[0][p * 64 + ((32 + fg * 8) ^ swzK)];
            f32x4 z = {};
            tt[s] = MFMA16(ka0, qf0, z);
            tt[s] = MFMA16(ka1, qf1, tt[s]);
        }
        __builtin_amdgcn_s_setprio(0);
        __syncthreads();   // all QK reads of Ks done before P overlay writes

        // raw-score max (upper bound incl. masked elems -> stability-safe)
        float pmax = -1e30f;
#pragma unroll
        for (int s = 0; s < 8; ++s)
#pragma unroll
            for (int j = 0; j < 4; ++j) pmax = fmaxf(pmax, tt[s][j]);
        if (__any(pmax > m_r + TH)) {
            pmax = fmaxf(pmax, __shfl_xor(pmax, 16));
            pmax = fmaxf(pmax, __shfl_xor(pmax, 32));
            const float mnew = fmaxf(m_r, pmax);
            const float scf = exp2f(m_r - mnew);
#pragma unroll
            for (int n = 0; n < 4; ++n)
#pragma unroll
                for (int j = 0; j < 4; ++j) acc[n][j] *= scf;
#pragma unroll
            for (int j = 0; j < 4; ++j) accl[j] *= scf;
            m_r = mnew;
        }
#pragma unroll
        for (int s = 0; s < 8; ++s)
#pragma unroll
            for (int j = 0; j < 4; ++j)
                tt[s][j] = exp2f(tt[s][j] - m_r);

        // pack P (cvt_pkrtz pairs along s), apply keep-mask, store to overlay
#pragma unroll
        for (int m = 0; m < 4; ++m) {
            half8 w;
#pragma unroll
            for (int a = 0; a < 4; ++a) {
                auto p2 = __builtin_amdgcn_cvt_pkrtz(tt[2 * a][m], tt[2 * a + 1][m]);
                w[2 * a] = (_Float16)p2[0]; w[2 * a + 1] = (_Float16)p2[1];
            }
            w *= mcur[m];   // v_pk_mul_f16: zero out masked keys
            *(half8*)&Pw[fr * 128 + ((fg * 32 + m * 8) ^ swzK)] = w;
        }

        // PV swapped: A = V rows (d), B = P^T -> D[d][q]; l via ones-MFMA
        __builtin_amdgcn_s_setprio(1);
#pragma unroll
        for (int c = 0; c < 4; ++c) {
            const half8 pa = *(const half8*)&Pw[fr * 128 + ((c * 32 + fg * 8) ^ swzK)];
            accl = MFMA16(ones8, pa, accl);
#pragma unroll
            for (int n = 0; n < 4; ++n) {
                const int d = n * 16 + fr;
                const half8 vb = *(const half8*)&Vs[0][d * 128 + ((c * 32 + fg * 8) ^ swzV)];
                acc[n] = MFMA16(vb, pa, acc[n]);
            }
        }
        __builtin_amdgcn_s_setprio(0);
#pragma unroll
        for (int n = 0; n < 4; ++n) mcur[n] = mnx[n];
    }

    const float inv = 1.0f / accl[0];
#pragma unroll
    for (int n = 0; n < 4; ++n) {
        half4v o = { (_Float16)(acc[n][0] * inv), (_Float16)(acc[n][1] * inv),
                     (_Float16)(acc[n][2] * inv), (_Float16)(acc[n][3] * inv) };
        *(half4v*)&ctx[((size_t)b * 2048 + q) * 1024 + h * 64 + n * 16 + fg * 4] = o;
    }
}

// LayerNorm over D=1024, one block per row (fp16 y in, fp32 out)
__global__ __launch_bounds__(256) void ln_kernel(
    const _Float16* __restrict__ y, const float* __restrict__ gamma,
    const float* __restrict__ beta, float* __restrict__ out) {
    const int row = blockIdx.x, tid = threadIdx.x;
    const size_t base = (size_t)row * 1024 + tid * 4;
    const half4v hv = *(const half4v*)(y + base);
    float4 v = { (float)hv[0], (float)hv[1], (float)hv[2], (float)hv[3] };
    float s = v.x + v.y + v.z + v.w;
    float ss = v.x * v.x + v.y * v.y + v.z * v.z + v.w * v.w;
#pragma unroll
    for (int o = 1; o < 64; o <<= 1) {
        s += __shfl_xor(s, o, 64);
        ss += __shfl_xor(ss, o, 64);
    }
    __shared__ float red[8];
    const int wid = tid >> 6;
    if ((tid & 63) == 0) { red[wid] = s; red[wid + 4] = ss; }
    __syncthreads();
    s = red[0] + red[1] + red[2] + red[3];
    ss = red[4] + red[5] + red[6] + red[7];
    const float mu = s * (1.0f / 1024.0f);
    const float var = ss * (1.0f / 1024.0f) - mu * mu;
    const float rstd = rsqrtf(var + 1e-5f);
    const float4 g = *(const float4*)(gamma + tid * 4);
    const float4 bt = *(const float4*)(beta + tid * 4);
    float4 o;
    o.x = (v.x - mu) * rstd * g.x + bt.x;
    o.y = (v.y - mu) * rstd * g.y + bt.y;
    o.z = (v.z - mu) * rstd * g.z + bt.z;
    o.w = (v.w - mu) * rstd * g.w + bt.w;
    *(float4*)(out + base) = o;
}

// ---------------------------------------------------------------------------
extern "C" void kernel_launch(void* const* d_in, const int* in_sizes, int n_in,
                              void* d_out, int out_size, void* d_ws, size_t ws_size,
                              hipStream_t stream) {
    (void)in_sizes; (void)n_in; (void)out_size; (void)ws_size;
    const float* q     = (const float*)d_in[0];
    const float* k     = (const float*)d_in[1];
    const float* v     = (const float*)d_in[2];
    const void*  mask  = d_in[3];
    const float* wq    = (const float*)d_in[4];
    const float* bq    = (const float*)d_in[5];
    const float* wk    = (const float*)d_in[6];
    const float* bk    = (const float*)d_in[7];
    const float* wv    = (const float*)d_in[8];
    const float* bv    = (const float*)d_in[9];
    const float* wo    = (const float*)d_in[10];
    const float* bo    = (const float*)d_in[11];
    const float* gamma = (const float*)d_in[12];
    const float* beta  = (const float*)d_in[13];

    char* ws = (char*)d_ws;
    constexpr size_t SZ_H = (size_t)4096 * 1024 * 2;   // 8 MiB (fp16 [4096][1024])
    constexpr size_t SZ_W = (size_t)1024 * 1024 * 2;   // 2 MiB (fp16 [1024][1024])
    size_t off = 256;
    _Float16* wt4 = (_Float16*)(ws + off); off += 4 * SZ_W;  // wq,wk,wv,wo transposed
    _Float16* scratchA = (_Float16*)(ws + off); off += SZ_H;  // ctx lives here
    _Float16* scratchB = (_Float16*)(ws + off); off += SZ_H;  // y (fp16, 8 MiB)
    _Float16* scratchC = (_Float16*)(ws + off); off += SZ_H;
    _Float16* Qh  = (_Float16*)(ws + off); off += SZ_H;
    _Float16* Kh  = (_Float16*)(ws + off); off += SZ_H;
    _Float16* Vh  = (_Float16*)(ws + off); off += SZ_H;
    _Float16* Vt  = (_Float16*)(ws + off); off += SZ_H;
    _Float16* km  = (_Float16*)(ws + off); off += (size_t)2 * 2048 * 2048 * 2;
    _Float16* wqt = wt4;
    _Float16* wot = wt4 + (size_t)3 * 1024 * 1024;
    _Float16* ctx = scratchA;
    _Float16* y   = scratchB;
    (void)scratchC;

    prep_kernel<<<12288, 256, 0, stream>>>(wq, wk, wv, wo, wt4, mask, km);

    gemm_qkv_kernel<<<dim3(32, 8, 3), 256, 0, stream>>>(q, k, v, wqt, bq, bk, bv, Qh);
    dim3 tb(32, 8);
    vtrans_kernel<<<dim3(2, 64, 32), tb, 0, stream>>>(Vh, Vt);
    attn_kernel<<<dim3(32, 32), 256, 0, stream>>>(Qh, Kh, Vt, km, ctx);
    gemm_out_kernel<<<dim3(64, 8), 256, 0, stream>>>(ctx, wot, bo, q, y);
    ln_kernel<<<4096, 256, 0, stream>>>(y, gamma, beta, (float*)d_out);
}